// Round 5
// baseline (1079.890 us; speedup 1.0000x reference)
//
#include <hip/hip_runtime.h>
#include <stdint.h>

#define NN 100000
#define NE 1600000
#define NPART 8

__device__ __forceinline__ void f4add(float4& a, const float4 v) {
    a.x += v.x; a.y += v.y; a.z += v.z; a.w += v.w;
}

// ---------------- CSR build ----------------
// 4 edges per thread (int4); partial histogram p = blockIdx & 7 to cut atomic
// same-line contention 8x. hist layout: [NPART][NN]
__global__ void hist_kernel(const int* __restrict__ ei, int* __restrict__ hist) {
    int t = blockIdx.x * blockDim.x + threadIdx.x;
    int e4 = t * 4;
    if (e4 >= NE) return;
    int* hp = hist + (size_t)(blockIdx.x & (NPART - 1)) * NN;
    int4 d = *(const int4*)(ei + NE + e4);
    atomicAdd(&hp[d.x], 1);
    atomicAdd(&hp[d.y], 1);
    atomicAdd(&hp[d.z], 1);
    atomicAdd(&hp[d.w], 1);
}

// per-block (1024 elems, 256 thr) exclusive scan over deg = sum_p hist_p
__global__ void scan_partial(const int* __restrict__ hist, int* __restrict__ excl,
                             int* __restrict__ bsums) {
    __shared__ int ts[256];
    int t = threadIdx.x;
    int base = blockIdx.x * 1024 + t * 4;
    int v0 = 0, v1 = 0, v2 = 0, v3 = 0;
    if (base < NN) {  // NN%4==0 so all-or-nothing
#pragma unroll
        for (int p = 0; p < NPART; ++p) {
            int4 v = *(const int4*)(hist + (size_t)p * NN + base);
            v0 += v.x; v1 += v.y; v2 += v.z; v3 += v.w;
        }
    }
    int s3 = v0 + v1 + v2 + v3;
    ts[t] = s3;
    __syncthreads();
    int sum = s3;
    for (int off = 1; off < 256; off <<= 1) {
        int x = (t >= off) ? ts[t - off] : 0;
        __syncthreads();
        sum += x;
        ts[t] = sum;
        __syncthreads();
    }
    if (t == 255) bsums[blockIdx.x] = sum;
    int pre = sum - s3;
    if (base < NN) {
        *(int4*)(excl + base) = make_int4(pre, pre + v0, pre + v0 + v1, pre + v0 + v1 + v2);
    }
}

__global__ void scan_sums(int* __restrict__ bsums, int nb) {  // 1 block, 128 thr
    __shared__ int ts[128];
    int t = threadIdx.x;
    int v = (t < nb) ? bsums[t] : 0;
    ts[t] = v;
    __syncthreads();
    int sum = v;
    for (int off = 1; off < 128; off <<= 1) {
        int x = (t >= off) ? ts[t - off] : 0;
        __syncthreads();
        sum += x;
        ts[t] = sum;
        __syncthreads();
    }
    if (t < nb) bsums[t] = sum - v;  // exclusive
}

// rowptr[i] = global exclusive prefix; cursors[p][i] = start of partial p's
// sub-segment within row i (order inside a row is irrelevant for a sum).
__global__ void scan_finalize(const int* __restrict__ excl, const int* __restrict__ bsums,
                              const int* __restrict__ hist,
                              int* __restrict__ rowptr, int* __restrict__ cursors) {
    int i = blockIdx.x * blockDim.x + threadIdx.x;
    if (i < NN) {
        int run = excl[i] + bsums[i >> 10];
        rowptr[i] = run;
#pragma unroll
        for (int p = 0; p < NPART; ++p) {
            cursors[(size_t)p * NN + i] = run;
            run += hist[(size_t)p * NN + i];
        }
    } else if (i == NN) {
        rowptr[NN] = NE;
    }
}

__global__ void fill_kernel(const int* __restrict__ ei, int* __restrict__ cursors,
                            int* __restrict__ esrc) {
    int t = blockIdx.x * blockDim.x + threadIdx.x;
    int e4 = t * 4;
    if (e4 >= NE) return;
    int* cp = cursors + (size_t)(blockIdx.x & (NPART - 1)) * NN;  // same p-map as hist
    int4 s = *(const int4*)(ei + e4);
    int4 d = *(const int4*)(ei + NE + e4);
    int pos;
    pos = atomicAdd(&cp[d.x], 1); esrc[pos] = s.x;
    pos = atomicAdd(&cp[d.y], 1); esrc[pos] = s.y;
    pos = atomicAdd(&cp[d.z], 1); esrc[pos] = s.z;
    pos = atomicAdd(&cp[d.w], 1); esrc[pos] = s.w;
}

// ---------------- SPMM (segment sum), 128-wide rows ----------------
// 16-lane group per node; lane covers 8 cols (2x float4); edge loop unrolled x4
// => 8 float4 loads in flight per lane (MLP for the latency-bound gather).
__global__ __launch_bounds__(256) void spmm128_kernel(
    const float* __restrict__ x, const int* __restrict__ rowptr,
    const int* __restrict__ esrc, float* __restrict__ rst) {
    int grp = (blockIdx.x * blockDim.x + threadIdx.x) >> 4;
    if (grp >= NN) return;
    const int sub = threadIdx.x & 15;
    const int gbase = threadIdx.x & 48;
    const size_t coff = (size_t)sub * 8;
    int start = rowptr[grp], end = rowptr[grp + 1];
    float4 a0 = make_float4(0.f, 0.f, 0.f, 0.f);
    float4 a1 = make_float4(0.f, 0.f, 0.f, 0.f);
    for (int j = start; j < end; j += 16) {
        int myidx = (j + sub < end) ? esrc[j + sub] : 0;
        int cnt = min(16, end - j);
        int q = 0;
        for (; q + 4 <= cnt; q += 4) {
            int s0 = __shfl(myidx, gbase + q);
            int s1 = __shfl(myidx, gbase + q + 1);
            int s2 = __shfl(myidx, gbase + q + 2);
            int s3 = __shfl(myidx, gbase + q + 3);
            const float* r0 = x + (size_t)s0 * 128 + coff;
            const float* r1 = x + (size_t)s1 * 128 + coff;
            const float* r2 = x + (size_t)s2 * 128 + coff;
            const float* r3 = x + (size_t)s3 * 128 + coff;
            float4 v00 = *(const float4*)r0;
            float4 v01 = *(const float4*)(r0 + 4);
            float4 v10 = *(const float4*)r1;
            float4 v11 = *(const float4*)(r1 + 4);
            float4 v20 = *(const float4*)r2;
            float4 v21 = *(const float4*)(r2 + 4);
            float4 v30 = *(const float4*)r3;
            float4 v31 = *(const float4*)(r3 + 4);
            f4add(a0, v00); f4add(a1, v01);
            f4add(a0, v10); f4add(a1, v11);
            f4add(a0, v20); f4add(a1, v21);
            f4add(a0, v30); f4add(a1, v31);
        }
        for (; q < cnt; ++q) {
            int s0 = __shfl(myidx, gbase + q);
            const float* r0 = x + (size_t)s0 * 128 + coff;
            f4add(a0, *(const float4*)r0);
            f4add(a1, *(const float4*)(r0 + 4));
        }
    }
    const float* xs = x + (size_t)grp * 128 + coff;
    f4add(a0, *(const float4*)xs);
    f4add(a1, *(const float4*)(xs + 4));
    float* rp = rst + (size_t)grp * 128 + coff;
    *(float4*)rp = a0;
    *(float4*)(rp + 4) = a1;
}

// ---------------- SPMM 40-wide with bias+self epilogue (final layer) ----------------
__global__ __launch_bounds__(256) void spmm40_kernel(
    const float* __restrict__ z, const int* __restrict__ rowptr,
    const int* __restrict__ esrc, const float* __restrict__ bout,
    float* __restrict__ out) {
    int grp = (blockIdx.x * blockDim.x + threadIdx.x) >> 4;
    if (grp >= NN) return;
    const int sub = threadIdx.x & 15;
    const int gbase = threadIdx.x & 48;
    const int c4 = sub * 4;  // only sub<10 meaningful; others read slack in ws
    int start = rowptr[grp], end = rowptr[grp + 1];
    float4 a = make_float4(0.f, 0.f, 0.f, 0.f);
    for (int j = start; j < end; j += 16) {
        int myidx = (j + sub < end) ? esrc[j + sub] : 0;
        int cnt = min(16, end - j);
        int q = 0;
        for (; q + 4 <= cnt; q += 4) {
            int s0 = __shfl(myidx, gbase + q);
            int s1 = __shfl(myidx, gbase + q + 1);
            int s2 = __shfl(myidx, gbase + q + 2);
            int s3 = __shfl(myidx, gbase + q + 3);
            float4 v0 = *(const float4*)(z + (size_t)s0 * 40 + c4);
            float4 v1 = *(const float4*)(z + (size_t)s1 * 40 + c4);
            float4 v2 = *(const float4*)(z + (size_t)s2 * 40 + c4);
            float4 v3 = *(const float4*)(z + (size_t)s3 * 40 + c4);
            f4add(a, v0); f4add(a, v1); f4add(a, v2); f4add(a, v3);
        }
        for (; q < cnt; ++q) {
            int s0 = __shfl(myidx, gbase + q);
            f4add(a, *(const float4*)(z + (size_t)s0 * 40 + c4));
        }
    }
    if (sub < 10) {
        float4 self = *(const float4*)(z + (size_t)grp * 40 + c4);
        float4 bb = *(const float4*)(bout + c4);
        float4 o;
        o.x = self.x + bb.x + a.x;
        o.y = self.y + bb.y + a.y;
        o.z = self.z + bb.z + a.z;
        o.w = self.w + bb.w + a.w;
        *(float4*)(out + (size_t)grp * 40 + c4) = o;
    }
}

// ---------------- GEMM: C[M][128] = A[M][128] @ W[128][128] + bias ----------------
__global__ __launch_bounds__(256) void gemm128_kernel(
    const float* __restrict__ A, const float* __restrict__ W,
    const float* __restrict__ bias, float* __restrict__ C, int M) {
    __shared__ float As[32][128];  // k-major
    __shared__ float Bs[32][128];
    const int t = threadIdx.x;
    const int br = blockIdx.x * 128;
    const int tm = (t >> 4) << 3;
    const int tn = (t & 15) << 3;
    const int lm = t & 127;
    const int lc0 = t >> 7;
    const int bk0 = t >> 5;
    const int bn = (t & 31) << 2;
    const int arow = min(br + lm, M - 1);
    const float* Ap = A + (size_t)arow * 128;

    float acc[8][8];
#pragma unroll
    for (int i = 0; i < 8; ++i)
#pragma unroll
        for (int j = 0; j < 8; ++j) acc[i][j] = 0.f;

    for (int k0 = 0; k0 < 128; k0 += 32) {
#pragma unroll
        for (int i = 0; i < 4; ++i) {
            int c = lc0 + 2 * i;
            float4 v = *(const float4*)(Ap + k0 + 4 * c);
            As[4 * c + 0][lm] = v.x;
            As[4 * c + 1][lm] = v.y;
            As[4 * c + 2][lm] = v.z;
            As[4 * c + 3][lm] = v.w;
        }
#pragma unroll
        for (int i = 0; i < 4; ++i) {
            int kk = bk0 + 8 * i;
            *(float4*)&Bs[kk][bn] = *(const float4*)(W + (size_t)(k0 + kk) * 128 + bn);
        }
        __syncthreads();
#pragma unroll
        for (int kk = 0; kk < 32; ++kk) {
            float a[8], b[8];
            *(float4*)&a[0] = *(const float4*)&As[kk][tm];
            *(float4*)&a[4] = *(const float4*)&As[kk][tm + 4];
            *(float4*)&b[0] = *(const float4*)&Bs[kk][tn];
            *(float4*)&b[4] = *(const float4*)&Bs[kk][tn + 4];
#pragma unroll
            for (int i = 0; i < 8; ++i)
#pragma unroll
                for (int j = 0; j < 8; ++j) acc[i][j] += a[i] * b[j];
        }
        __syncthreads();
    }
#pragma unroll
    for (int i = 0; i < 8; ++i) {
        int row = br + tm + i;
        if (row < M) {
            float4 o0, o1;
            o0.x = acc[i][0] + bias[tn + 0];
            o0.y = acc[i][1] + bias[tn + 1];
            o0.z = acc[i][2] + bias[tn + 2];
            o0.w = acc[i][3] + bias[tn + 3];
            o1.x = acc[i][4] + bias[tn + 4];
            o1.y = acc[i][5] + bias[tn + 5];
            o1.z = acc[i][6] + bias[tn + 6];
            o1.w = acc[i][7] + bias[tn + 7];
            *(float4*)(C + (size_t)row * 128 + tn) = o0;
            *(float4*)(C + (size_t)row * 128 + tn + 4) = o1;
        }
    }
}

// ---------------- GEMM: Z[M][40] = A[M][128] @ W[128][40] (no bias) ----------------
__global__ __launch_bounds__(256) void gemm40_kernel(
    const float* __restrict__ A, const float* __restrict__ W,
    float* __restrict__ Z, int M) {
    __shared__ float As[64][132];
    __shared__ float Wls[128 * 40];
    const int t = threadIdx.x;
    const int br = blockIdx.x * 64;
#pragma unroll
    for (int i = 0; i < 5; ++i) {
        int idx = t + 256 * i;
        *(float4*)&Wls[idx * 4] = *(const float4*)(W + idx * 4);
    }
    {
        int r = t >> 2;
        int row = min(br + r, M - 1);
        const float* Ap = A + (size_t)row * 128;
#pragma unroll
        for (int i = 0; i < 8; ++i) {
            int c = (t & 3) + 4 * i;
            float4 v = *(const float4*)(Ap + 4 * c);
            *(float4*)&As[r][4 * c] = v;
        }
    }
    __syncthreads();
    const int tm2 = (t >> 3) * 2;
    const int tn5 = (t & 7) * 5;
    float acc[2][5];
#pragma unroll
    for (int i = 0; i < 2; ++i)
#pragma unroll
        for (int j = 0; j < 5; ++j) acc[i][j] = 0.f;
#pragma unroll 4
    for (int kk = 0; kk < 128; ++kk) {
        float a0 = As[tm2][kk], a1 = As[tm2 + 1][kk];
#pragma unroll
        for (int j = 0; j < 5; ++j) {
            float b = Wls[kk * 40 + tn5 + j];
            acc[0][j] += a0 * b;
            acc[1][j] += a1 * b;
        }
    }
#pragma unroll
    for (int i = 0; i < 2; ++i) {
        int row = br + tm2 + i;
        if (row < M) {
#pragma unroll
            for (int j = 0; j < 5; ++j) Z[(size_t)row * 40 + tn5 + j] = acc[i][j];
        }
    }
}

extern "C" void kernel_launch(void* const* d_in, const int* in_sizes, int n_in,
                              void* d_out, int out_size, void* d_ws, size_t ws_size,
                              hipStream_t stream) {
    const float* h      = (const float*)d_in[0];
    const float* Ws     = (const float*)d_in[1];
    const float* bs     = (const float*)d_in[2];
    const float* W_out  = (const float*)d_in[3];
    const float* b_out  = (const float*)d_in[4];
    const int*   ei     = (const int*)d_in[5];
    float* out = (float*)d_out;

    char* p = (char*)d_ws;
    auto alloc = [&](size_t bytes) {
        char* r = p;
        p += (bytes + 255) & ~size_t(255);
        return r;
    };
    int* hist    = (int*)alloc((size_t)NPART * NN * 4);   // 3.2 MB
    int* cursors = (int*)alloc((size_t)NPART * NN * 4);   // 3.2 MB
    int* rowptr  = (int*)alloc((size_t)(NN + 1) * 4);
    int* bsums   = (int*)alloc(128 * 4);
    int* esrc    = (int*)alloc((size_t)NE * 4);
    float* R     = (float*)alloc((size_t)NN * 128 * 4);
    float* H     = (float*)alloc((size_t)NN * 128 * 4);

    // ---- CSR build ----
    hipMemsetAsync(hist, 0, (size_t)NPART * NN * 4, stream);
    const int eblocks = (NE / 4 + 255) / 256;  // 4 edges per thread
    hist_kernel<<<eblocks, 256, 0, stream>>>(ei, hist);
    int nb = (NN + 1023) / 1024;  // 98
    scan_partial<<<nb, 256, 0, stream>>>(hist, esrc /*reuse as excl scratch*/, bsums);
    scan_sums<<<1, 128, 0, stream>>>(bsums, nb);
    scan_finalize<<<(NN + 256) / 256, 256, 0, stream>>>(esrc, bsums, hist, rowptr, cursors);
    fill_kernel<<<eblocks, 256, 0, stream>>>(ei, cursors, esrc);

    // ---- layers 0..3 ----
    const int spmm_grid = (NN * 16 + 255) / 256;
    const float* x = h;
    for (int l = 0; l < 4; ++l) {
        spmm128_kernel<<<spmm_grid, 256, 0, stream>>>(x, rowptr, esrc, R);
        gemm128_kernel<<<(NN + 127) / 128, 256, 0, stream>>>(
            R, Ws + (size_t)l * 128 * 128, bs + (size_t)l * 128, H, NN);
        x = H;
    }
    // ---- layer 4 (GEMM first, then 40-wide aggregate) ----
    gemm40_kernel<<<(NN + 63) / 64, 256, 0, stream>>>(H, W_out, R, NN);
    spmm40_kernel<<<spmm_grid, 256, 0, stream>>>(R, rowptr, esrc, b_out, out);
}

// Round 6
// 799.616 us; speedup vs baseline: 1.3505x; 1.3505x over previous
//
#include <hip/hip_runtime.h>
#include <hip/hip_fp16.h>
#include <stdint.h>

#define NN 100000
#define NE 1600000
#define NPART 8

__device__ __forceinline__ void h8acc(float* a, uint4 v) {
    const __half2* h = (const __half2*)&v;
#pragma unroll
    for (int k = 0; k < 4; ++k) {
        float2 f = __half22float2(h[k]);
        a[2 * k] += f.x;
        a[2 * k + 1] += f.y;
    }
}

// ---------------- CSR build ----------------
__global__ void hist_kernel(const int* __restrict__ ei, int* __restrict__ hist) {
    int t = blockIdx.x * blockDim.x + threadIdx.x;
    int e4 = t * 4;
    if (e4 >= NE) return;
    int* hp = hist + (size_t)(blockIdx.x & (NPART - 1)) * NN;
    int4 d = *(const int4*)(ei + NE + e4);
    atomicAdd(&hp[d.x], 1);
    atomicAdd(&hp[d.y], 1);
    atomicAdd(&hp[d.z], 1);
    atomicAdd(&hp[d.w], 1);
}

__global__ void scan_partial(const int* __restrict__ hist, int* __restrict__ excl,
                             int* __restrict__ bsums) {
    __shared__ int ts[256];
    int t = threadIdx.x;
    int base = blockIdx.x * 1024 + t * 4;
    int v0 = 0, v1 = 0, v2 = 0, v3 = 0;
    if (base < NN) {  // NN%4==0
#pragma unroll
        for (int p = 0; p < NPART; ++p) {
            int4 v = *(const int4*)(hist + (size_t)p * NN + base);
            v0 += v.x; v1 += v.y; v2 += v.z; v3 += v.w;
        }
    }
    int s3 = v0 + v1 + v2 + v3;
    ts[t] = s3;
    __syncthreads();
    int sum = s3;
    for (int off = 1; off < 256; off <<= 1) {
        int x = (t >= off) ? ts[t - off] : 0;
        __syncthreads();
        sum += x;
        ts[t] = sum;
        __syncthreads();
    }
    if (t == 255) bsums[blockIdx.x] = sum;
    int pre = sum - s3;
    if (base < NN) {
        *(int4*)(excl + base) = make_int4(pre, pre + v0, pre + v0 + v1, pre + v0 + v1 + v2);
    }
}

__global__ void scan_sums(int* __restrict__ bsums, int nb) {
    __shared__ int ts[128];
    int t = threadIdx.x;
    int v = (t < nb) ? bsums[t] : 0;
    ts[t] = v;
    __syncthreads();
    int sum = v;
    for (int off = 1; off < 128; off <<= 1) {
        int x = (t >= off) ? ts[t - off] : 0;
        __syncthreads();
        sum += x;
        ts[t] = sum;
        __syncthreads();
    }
    if (t < nb) bsums[t] = sum - v;
}

__global__ void scan_finalize(const int* __restrict__ excl, const int* __restrict__ bsums,
                              const int* __restrict__ hist,
                              int* __restrict__ rowptr, int* __restrict__ cursors) {
    int i = blockIdx.x * blockDim.x + threadIdx.x;
    if (i < NN) {
        int run = excl[i] + bsums[i >> 10];
        rowptr[i] = run;
#pragma unroll
        for (int p = 0; p < NPART; ++p) {
            cursors[(size_t)p * NN + i] = run;
            run += hist[(size_t)p * NN + i];
        }
    } else if (i == NN) {
        rowptr[NN] = NE;
    }
}

__global__ void fill_kernel(const int* __restrict__ ei, int* __restrict__ cursors,
                            int* __restrict__ esrc) {
    int t = blockIdx.x * blockDim.x + threadIdx.x;
    int e4 = t * 4;
    if (e4 >= NE) return;
    int* cp = cursors + (size_t)(blockIdx.x & (NPART - 1)) * NN;
    int4 s = *(const int4*)(ei + e4);
    int4 d = *(const int4*)(ei + NE + e4);
    int pos;
    pos = atomicAdd(&cp[d.x], 1); esrc[pos] = s.x;
    pos = atomicAdd(&cp[d.y], 1); esrc[pos] = s.y;
    pos = atomicAdd(&cp[d.z], 1); esrc[pos] = s.z;
    pos = atomicAdd(&cp[d.w], 1); esrc[pos] = s.w;
}

// ---------------- convert h (fp32) -> fp16 ----------------
__global__ void cvt16_kernel(const float* __restrict__ in, __half* __restrict__ out16) {
    size_t i = (size_t)(blockIdx.x * blockDim.x + threadIdx.x) * 8;
    if (i >= (size_t)NN * 128) return;
    float4 v0 = *(const float4*)(in + i);
    float4 v1 = *(const float4*)(in + i + 4);
    uint4 o;
    __half2* oh = (__half2*)&o;
    oh[0] = __float22half2_rn(make_float2(v0.x, v0.y));
    oh[1] = __float22half2_rn(make_float2(v0.z, v0.w));
    oh[2] = __float22half2_rn(make_float2(v1.x, v1.y));
    oh[3] = __float22half2_rn(make_float2(v1.z, v1.w));
    *(uint4*)(out16 + i) = o;
}

// ---------------- SPMM: x' = y + agg(y) + b, all via fp16 y ----------------
// 16-lane group per node; lane covers 8 cols (one uint4 = 8 halfs); unroll x4.
__global__ __launch_bounds__(256) void spmm128_kernel(
    const __half* __restrict__ y16, const int* __restrict__ rowptr,
    const int* __restrict__ esrc, const float* __restrict__ bias,
    __half* __restrict__ x16) {
    int grp = (blockIdx.x * blockDim.x + threadIdx.x) >> 4;
    if (grp >= NN) return;
    const int sub = threadIdx.x & 15;
    const int gbase = threadIdx.x & 48;
    const int hoff = sub * 8;
    int start = rowptr[grp], end = rowptr[grp + 1];
    float a[8];
#pragma unroll
    for (int k = 0; k < 8; ++k) a[k] = 0.f;
    for (int j = start; j < end; j += 16) {
        int myidx = (j + sub < end) ? esrc[j + sub] : 0;
        int cnt = min(16, end - j);
        int q = 0;
        for (; q + 4 <= cnt; q += 4) {
            int s0 = __shfl(myidx, gbase + q);
            int s1 = __shfl(myidx, gbase + q + 1);
            int s2 = __shfl(myidx, gbase + q + 2);
            int s3 = __shfl(myidx, gbase + q + 3);
            uint4 v0 = *(const uint4*)(y16 + (size_t)s0 * 128 + hoff);
            uint4 v1 = *(const uint4*)(y16 + (size_t)s1 * 128 + hoff);
            uint4 v2 = *(const uint4*)(y16 + (size_t)s2 * 128 + hoff);
            uint4 v3 = *(const uint4*)(y16 + (size_t)s3 * 128 + hoff);
            h8acc(a, v0); h8acc(a, v1); h8acc(a, v2); h8acc(a, v3);
        }
        for (; q < cnt; ++q) {
            int s0 = __shfl(myidx, gbase + q);
            h8acc(a, *(const uint4*)(y16 + (size_t)s0 * 128 + hoff));
        }
    }
    // self + bias
    h8acc(a, *(const uint4*)(y16 + (size_t)grp * 128 + hoff));
    float4 b0 = *(const float4*)(bias + hoff);
    float4 b1 = *(const float4*)(bias + hoff + 4);
    a[0] += b0.x; a[1] += b0.y; a[2] += b0.z; a[3] += b0.w;
    a[4] += b1.x; a[5] += b1.y; a[6] += b1.z; a[7] += b1.w;
    uint4 o;
    __half2* oh = (__half2*)&o;
#pragma unroll
    for (int k = 0; k < 4; ++k)
        oh[k] = __float22half2_rn(make_float2(a[2 * k], a[2 * k + 1]));
    *(uint4*)(x16 + (size_t)grp * 128 + hoff) = o;
}

// ---------------- SPMM 40-wide final: out = z + agg(z) + b_out (fp32 out) ----------------
__global__ __launch_bounds__(256) void spmm40_kernel(
    const __half* __restrict__ z16, const int* __restrict__ rowptr,
    const int* __restrict__ esrc, const float* __restrict__ bout,
    float* __restrict__ out) {
    int grp = (blockIdx.x * blockDim.x + threadIdx.x) >> 4;
    if (grp >= NN) return;
    const int sub = threadIdx.x & 15;
    const int gbase = threadIdx.x & 48;
    const int hoff = sub * 4;  // halfs; only sub<10 meaningful
    int start = rowptr[grp], end = rowptr[grp + 1];
    float a[4];
#pragma unroll
    for (int k = 0; k < 4; ++k) a[k] = 0.f;
    for (int j = start; j < end; j += 16) {
        int myidx = (j + sub < end) ? esrc[j + sub] : 0;
        int cnt = min(16, end - j);
        int q = 0;
        for (; q + 4 <= cnt; q += 4) {
            int s0 = __shfl(myidx, gbase + q);
            int s1 = __shfl(myidx, gbase + q + 1);
            int s2 = __shfl(myidx, gbase + q + 2);
            int s3 = __shfl(myidx, gbase + q + 3);
            uint2 v0 = *(const uint2*)(z16 + (size_t)s0 * 40 + hoff);
            uint2 v1 = *(const uint2*)(z16 + (size_t)s1 * 40 + hoff);
            uint2 v2 = *(const uint2*)(z16 + (size_t)s2 * 40 + hoff);
            uint2 v3 = *(const uint2*)(z16 + (size_t)s3 * 40 + hoff);
            const __half2* h;
            h = (const __half2*)&v0;
            { float2 f = __half22float2(h[0]); a[0]+=f.x; a[1]+=f.y; f = __half22float2(h[1]); a[2]+=f.x; a[3]+=f.y; }
            h = (const __half2*)&v1;
            { float2 f = __half22float2(h[0]); a[0]+=f.x; a[1]+=f.y; f = __half22float2(h[1]); a[2]+=f.x; a[3]+=f.y; }
            h = (const __half2*)&v2;
            { float2 f = __half22float2(h[0]); a[0]+=f.x; a[1]+=f.y; f = __half22float2(h[1]); a[2]+=f.x; a[3]+=f.y; }
            h = (const __half2*)&v3;
            { float2 f = __half22float2(h[0]); a[0]+=f.x; a[1]+=f.y; f = __half22float2(h[1]); a[2]+=f.x; a[3]+=f.y; }
        }
        for (; q < cnt; ++q) {
            int s0 = __shfl(myidx, gbase + q);
            uint2 v0 = *(const uint2*)(z16 + (size_t)s0 * 40 + hoff);
            const __half2* h = (const __half2*)&v0;
            float2 f = __half22float2(h[0]); a[0]+=f.x; a[1]+=f.y;
            f = __half22float2(h[1]); a[2]+=f.x; a[3]+=f.y;
        }
    }
    if (sub < 10) {
        uint2 sv = *(const uint2*)(z16 + (size_t)grp * 40 + hoff);
        const __half2* h = (const __half2*)&sv;
        float2 f0 = __half22float2(h[0]);
        float2 f1 = __half22float2(h[1]);
        float4 bb = *(const float4*)(bout + hoff);
        float4 o;
        o.x = f0.x + bb.x + a[0];
        o.y = f0.y + bb.y + a[1];
        o.z = f1.x + bb.z + a[2];
        o.w = f1.y + bb.w + a[3];
        *(float4*)(out + (size_t)grp * 40 + hoff) = o;
    }
}

// ---------------- GEMM: Y16[M][128] = fp16( A16[M][128] @ W[128][128] ) ----------------
__global__ __launch_bounds__(256) void gemm128_kernel(
    const __half* __restrict__ A16, const float* __restrict__ W,
    __half* __restrict__ Y16, int M) {
    __shared__ float As[32][128];  // k-major
    __shared__ float Bs[32][128];
    const int t = threadIdx.x;
    const int br = blockIdx.x * 128;
    const int tm = (t >> 4) << 3;
    const int tn = (t & 15) << 3;
    const int lm = t & 127;
    const int lc0 = t >> 7;         // 0 or 1
    const int bk0 = t >> 5;
    const int bn = (t & 31) << 2;
    const int arow = min(br + lm, M - 1);
    const __half* Ap = A16 + (size_t)arow * 128;

    float acc[8][8];
#pragma unroll
    for (int i = 0; i < 8; ++i)
#pragma unroll
        for (int j = 0; j < 8; ++j) acc[i][j] = 0.f;

    for (int k0 = 0; k0 < 128; k0 += 32) {
#pragma unroll
        for (int i = 0; i < 2; ++i) {
            int c = lc0 + 2 * i;  // chunk 0..3, 8 halfs each
            uint4 v = *(const uint4*)(Ap + k0 + 8 * c);
            const __half2* h = (const __half2*)&v;
#pragma unroll
            for (int k = 0; k < 4; ++k) {
                float2 f = __half22float2(h[k]);
                As[8 * c + 2 * k][lm] = f.x;
                As[8 * c + 2 * k + 1][lm] = f.y;
            }
        }
#pragma unroll
        for (int i = 0; i < 4; ++i) {
            int kk = bk0 + 8 * i;
            *(float4*)&Bs[kk][bn] = *(const float4*)(W + (size_t)(k0 + kk) * 128 + bn);
        }
        __syncthreads();
#pragma unroll
        for (int kk = 0; kk < 32; ++kk) {
            float a[8], b[8];
            *(float4*)&a[0] = *(const float4*)&As[kk][tm];
            *(float4*)&a[4] = *(const float4*)&As[kk][tm + 4];
            *(float4*)&b[0] = *(const float4*)&Bs[kk][tn];
            *(float4*)&b[4] = *(const float4*)&Bs[kk][tn + 4];
#pragma unroll
            for (int i = 0; i < 8; ++i)
#pragma unroll
                for (int j = 0; j < 8; ++j) acc[i][j] += a[i] * b[j];
        }
        __syncthreads();
    }
#pragma unroll
    for (int i = 0; i < 8; ++i) {
        int row = br + tm + i;
        if (row < M) {
            uint4 o;
            __half2* oh = (__half2*)&o;
#pragma unroll
            for (int k = 0; k < 4; ++k)
                oh[k] = __float22half2_rn(make_float2(acc[i][2 * k], acc[i][2 * k + 1]));
            *(uint4*)(Y16 + (size_t)row * 128 + tn) = o;
        }
    }
}

// ---------------- GEMM: Z16[M][40] = fp16( A16[M][128] @ W[128][40] ) ----------------
__global__ __launch_bounds__(256) void gemm40_kernel(
    const __half* __restrict__ A16, const float* __restrict__ W,
    __half* __restrict__ Z16, int M) {
    __shared__ float As[64][132];
    __shared__ float Wls[128 * 40];
    const int t = threadIdx.x;
    const int br = blockIdx.x * 64;
#pragma unroll
    for (int i = 0; i < 5; ++i) {
        int idx = t + 256 * i;  // 1280 float4s
        *(float4*)&Wls[idx * 4] = *(const float4*)(W + idx * 4);
    }
    {
        int r = t >> 2;
        int row = min(br + r, M - 1);
        const __half* Ap = A16 + (size_t)row * 128;
#pragma unroll
        for (int i = 0; i < 4; ++i) {
            int c = (t & 3) + 4 * i;  // chunk 0..15, 8 halfs each
            uint4 v = *(const uint4*)(Ap + 8 * c);
            const __half2* h = (const __half2*)&v;
#pragma unroll
            for (int k = 0; k < 4; ++k) {
                float2 f = __half22float2(h[k]);
                As[r][8 * c + 2 * k] = f.x;
                As[r][8 * c + 2 * k + 1] = f.y;
            }
        }
    }
    __syncthreads();
    const int r = t >> 2;          // row 0..63
    const int tn10 = (t & 3) * 10; // col 0,10,20,30
    float acc[10];
#pragma unroll
    for (int j = 0; j < 10; ++j) acc[j] = 0.f;
#pragma unroll 4
    for (int kk = 0; kk < 128; ++kk) {
        float a0 = As[r][kk];
        const float* wp = &Wls[kk * 40 + tn10];
#pragma unroll
        for (int j = 0; j < 10; ++j) acc[j] += a0 * wp[j];
    }
    int row = br + r;
    if (row < M) {
        __half* zp = Z16 + (size_t)row * 40 + tn10;
#pragma unroll
        for (int j = 0; j < 5; ++j) {
            __half2 hv = __float22half2_rn(make_float2(acc[2 * j], acc[2 * j + 1]));
            *(uint*)( (char*)zp + 4 * j ) = *(uint*)&hv;  // 4B-aligned half2 store
        }
    }
}

extern "C" void kernel_launch(void* const* d_in, const int* in_sizes, int n_in,
                              void* d_out, int out_size, void* d_ws, size_t ws_size,
                              hipStream_t stream) {
    const float* h      = (const float*)d_in[0];
    const float* Ws     = (const float*)d_in[1];
    const float* bs     = (const float*)d_in[2];
    const float* W_out  = (const float*)d_in[3];
    const float* b_out  = (const float*)d_in[4];
    const int*   ei     = (const int*)d_in[5];
    float* out = (float*)d_out;

    char* p = (char*)d_ws;
    auto alloc = [&](size_t bytes) {
        char* r = p;
        p += (bytes + 255) & ~size_t(255);
        return r;
    };
    int* hist    = (int*)alloc((size_t)NPART * NN * 4);       // 3.2 MB
    int* cursors = (int*)alloc((size_t)NPART * NN * 4);       // 3.2 MB
    int* rowptr  = (int*)alloc((size_t)(NN + 1) * 4);
    int* bsums   = (int*)alloc(128 * 4);
    int* esrc    = (int*)alloc((size_t)NE * 4);               // 6.4 MB
    __half* X16  = (__half*)alloc((size_t)NN * 128 * 2);      // 25.6 MB
    __half* Y16  = (__half*)alloc((size_t)NN * 128 * 2 + 256);// 25.6 MB (Z16 reuses, +slack)

    // ---- CSR build ----
    hipMemsetAsync(hist, 0, (size_t)NPART * NN * 4, stream);
    const int eblocks = (NE / 4 + 255) / 256;
    hist_kernel<<<eblocks, 256, 0, stream>>>(ei, hist);
    int nb = (NN + 1023) / 1024;  // 98
    scan_partial<<<nb, 256, 0, stream>>>(hist, esrc /*scratch*/, bsums);
    scan_sums<<<1, 128, 0, stream>>>(bsums, nb);
    scan_finalize<<<(NN + 256) / 256, 256, 0, stream>>>(esrc, bsums, hist, rowptr, cursors);
    fill_kernel<<<eblocks, 256, 0, stream>>>(ei, cursors, esrc);

    // ---- h -> fp16 ----
    cvt16_kernel<<<(NN * 128 / 8 + 255) / 256, 256, 0, stream>>>(h, X16);

    // ---- layers 0..3: y = x@W (fp16 out); x' = y + agg(y) + b ----
    const int spmm_grid = (NN * 16 + 255) / 256;
    for (int l = 0; l < 4; ++l) {
        gemm128_kernel<<<(NN + 127) / 128, 256, 0, stream>>>(
            X16, Ws + (size_t)l * 128 * 128, Y16, NN);
        spmm128_kernel<<<spmm_grid, 256, 0, stream>>>(
            Y16, rowptr, esrc, bs + (size_t)l * 128, X16);
    }
    // ---- layer 4: z = x4@W_out; out = z + agg(z) + b_out ----
    gemm40_kernel<<<(NN + 63) / 64, 256, 0, stream>>>(X16, W_out, Y16 /*as Z16*/, NN);
    spmm40_kernel<<<spmm_grid, 256, 0, stream>>>(Y16, rowptr, esrc, b_out, out);
}

// Round 7
// 704.659 us; speedup vs baseline: 1.5325x; 1.1348x over previous
//
#include <hip/hip_runtime.h>
#include <hip/hip_fp16.h>
#include <stdint.h>

#define NN 100000
#define NE 1600000
#define NPART 8

typedef _Float16 f16x8 __attribute__((ext_vector_type(8)));
typedef float f32x4 __attribute__((ext_vector_type(4)));

__device__ __forceinline__ void h8acc(float* a, uint4 v) {
    const __half2* h = (const __half2*)&v;
#pragma unroll
    for (int k = 0; k < 4; ++k) {
        float2 f = __half22float2(h[k]);
        a[2 * k] += f.x;
        a[2 * k + 1] += f.y;
    }
}

// ---------------- CSR build ----------------
__global__ void hist_kernel(const int* __restrict__ ei, int* __restrict__ hist) {
    int t = blockIdx.x * blockDim.x + threadIdx.x;
    int e4 = t * 4;
    if (e4 >= NE) return;
    int* hp = hist + (size_t)(blockIdx.x & (NPART - 1)) * NN;
    int4 d = *(const int4*)(ei + NE + e4);
    atomicAdd(&hp[d.x], 1);
    atomicAdd(&hp[d.y], 1);
    atomicAdd(&hp[d.z], 1);
    atomicAdd(&hp[d.w], 1);
}

__global__ void scan_partial(const int* __restrict__ hist, int* __restrict__ excl,
                             int* __restrict__ bsums) {
    __shared__ int ts[256];
    int t = threadIdx.x;
    int base = blockIdx.x * 1024 + t * 4;
    int v0 = 0, v1 = 0, v2 = 0, v3 = 0;
    if (base < NN) {  // NN%4==0
#pragma unroll
        for (int p = 0; p < NPART; ++p) {
            int4 v = *(const int4*)(hist + (size_t)p * NN + base);
            v0 += v.x; v1 += v.y; v2 += v.z; v3 += v.w;
        }
    }
    int s3 = v0 + v1 + v2 + v3;
    ts[t] = s3;
    __syncthreads();
    int sum = s3;
    for (int off = 1; off < 256; off <<= 1) {
        int x = (t >= off) ? ts[t - off] : 0;
        __syncthreads();
        sum += x;
        ts[t] = sum;
        __syncthreads();
    }
    if (t == 255) bsums[blockIdx.x] = sum;
    int pre = sum - s3;
    if (base < NN) {
        *(int4*)(excl + base) = make_int4(pre, pre + v0, pre + v0 + v1, pre + v0 + v1 + v2);
    }
}

__global__ void scan_sums(int* __restrict__ bsums, int nb) {
    __shared__ int ts[128];
    int t = threadIdx.x;
    int v = (t < nb) ? bsums[t] : 0;
    ts[t] = v;
    __syncthreads();
    int sum = v;
    for (int off = 1; off < 128; off <<= 1) {
        int x = (t >= off) ? ts[t - off] : 0;
        __syncthreads();
        sum += x;
        ts[t] = sum;
        __syncthreads();
    }
    if (t < nb) bsums[t] = sum - v;
}

__global__ void scan_finalize(const int* __restrict__ excl, const int* __restrict__ bsums,
                              const int* __restrict__ hist,
                              int* __restrict__ rowptr, int* __restrict__ cursors) {
    int i = blockIdx.x * blockDim.x + threadIdx.x;
    if (i < NN) {
        int run = excl[i] + bsums[i >> 10];
        rowptr[i] = run;
#pragma unroll
        for (int p = 0; p < NPART; ++p) {
            cursors[(size_t)p * NN + i] = run;
            run += hist[(size_t)p * NN + i];
        }
    } else if (i == NN) {
        rowptr[NN] = NE;
    }
}

__global__ void fill_kernel(const int* __restrict__ ei, int* __restrict__ cursors,
                            int* __restrict__ esrc) {
    int t = blockIdx.x * blockDim.x + threadIdx.x;
    int e4 = t * 4;
    if (e4 >= NE) return;
    int* cp = cursors + (size_t)(blockIdx.x & (NPART - 1)) * NN;
    int4 s = *(const int4*)(ei + e4);
    int4 d = *(const int4*)(ei + NE + e4);
    int pos;
    pos = atomicAdd(&cp[d.x], 1); esrc[pos] = s.x;
    pos = atomicAdd(&cp[d.y], 1); esrc[pos] = s.y;
    pos = atomicAdd(&cp[d.z], 1); esrc[pos] = s.z;
    pos = atomicAdd(&cp[d.w], 1); esrc[pos] = s.w;
}

// ---------------- convert h (fp32) -> fp16 ----------------
__global__ void cvt16_kernel(const float* __restrict__ in, __half* __restrict__ out16) {
    size_t i = (size_t)(blockIdx.x * blockDim.x + threadIdx.x) * 8;
    if (i >= (size_t)NN * 128) return;
    float4 v0 = *(const float4*)(in + i);
    float4 v1 = *(const float4*)(in + i + 4);
    uint4 o;
    __half2* oh = (__half2*)&o;
    oh[0] = __float22half2_rn(make_float2(v0.x, v0.y));
    oh[1] = __float22half2_rn(make_float2(v0.z, v0.w));
    oh[2] = __float22half2_rn(make_float2(v1.x, v1.y));
    oh[3] = __float22half2_rn(make_float2(v1.z, v1.w));
    *(uint4*)(out16 + i) = o;
}

// ---------------- SPMM: x' = y + agg(y) + b, all via fp16 y ----------------
__global__ __launch_bounds__(256) void spmm128_kernel(
    const __half* __restrict__ y16, const int* __restrict__ rowptr,
    const int* __restrict__ esrc, const float* __restrict__ bias,
    __half* __restrict__ x16) {
    int grp = (blockIdx.x * blockDim.x + threadIdx.x) >> 4;
    if (grp >= NN) return;
    const int sub = threadIdx.x & 15;
    const int gbase = threadIdx.x & 48;
    const int hoff = sub * 8;
    int start = rowptr[grp], end = rowptr[grp + 1];
    float a[8];
#pragma unroll
    for (int k = 0; k < 8; ++k) a[k] = 0.f;
    for (int j = start; j < end; j += 16) {
        int myidx = (j + sub < end) ? esrc[j + sub] : 0;
        int cnt = min(16, end - j);
        int q = 0;
        for (; q + 4 <= cnt; q += 4) {
            int s0 = __shfl(myidx, gbase + q);
            int s1 = __shfl(myidx, gbase + q + 1);
            int s2 = __shfl(myidx, gbase + q + 2);
            int s3 = __shfl(myidx, gbase + q + 3);
            uint4 v0 = *(const uint4*)(y16 + (size_t)s0 * 128 + hoff);
            uint4 v1 = *(const uint4*)(y16 + (size_t)s1 * 128 + hoff);
            uint4 v2 = *(const uint4*)(y16 + (size_t)s2 * 128 + hoff);
            uint4 v3 = *(const uint4*)(y16 + (size_t)s3 * 128 + hoff);
            h8acc(a, v0); h8acc(a, v1); h8acc(a, v2); h8acc(a, v3);
        }
        for (; q < cnt; ++q) {
            int s0 = __shfl(myidx, gbase + q);
            h8acc(a, *(const uint4*)(y16 + (size_t)s0 * 128 + hoff));
        }
    }
    h8acc(a, *(const uint4*)(y16 + (size_t)grp * 128 + hoff));
    float4 b0 = *(const float4*)(bias + hoff);
    float4 b1 = *(const float4*)(bias + hoff + 4);
    a[0] += b0.x; a[1] += b0.y; a[2] += b0.z; a[3] += b0.w;
    a[4] += b1.x; a[5] += b1.y; a[6] += b1.z; a[7] += b1.w;
    uint4 o;
    __half2* oh = (__half2*)&o;
#pragma unroll
    for (int k = 0; k < 4; ++k)
        oh[k] = __float22half2_rn(make_float2(a[2 * k], a[2 * k + 1]));
    *(uint4*)(x16 + (size_t)grp * 128 + hoff) = o;
}

// ---------------- SPMM 40-wide final: out = z + agg(z) + b_out (fp32 out) ----------------
__global__ __launch_bounds__(256) void spmm40_kernel(
    const __half* __restrict__ z16, const int* __restrict__ rowptr,
    const int* __restrict__ esrc, const float* __restrict__ bout,
    float* __restrict__ out) {
    int grp = (blockIdx.x * blockDim.x + threadIdx.x) >> 4;
    if (grp >= NN) return;
    const int sub = threadIdx.x & 15;
    const int gbase = threadIdx.x & 48;
    const int hoff = sub * 4;
    int start = rowptr[grp], end = rowptr[grp + 1];
    float a[4];
#pragma unroll
    for (int k = 0; k < 4; ++k) a[k] = 0.f;
    for (int j = start; j < end; j += 16) {
        int myidx = (j + sub < end) ? esrc[j + sub] : 0;
        int cnt = min(16, end - j);
        int q = 0;
        for (; q + 4 <= cnt; q += 4) {
            int s0 = __shfl(myidx, gbase + q);
            int s1 = __shfl(myidx, gbase + q + 1);
            int s2 = __shfl(myidx, gbase + q + 2);
            int s3 = __shfl(myidx, gbase + q + 3);
            uint2 v0 = *(const uint2*)(z16 + (size_t)s0 * 40 + hoff);
            uint2 v1 = *(const uint2*)(z16 + (size_t)s1 * 40 + hoff);
            uint2 v2 = *(const uint2*)(z16 + (size_t)s2 * 40 + hoff);
            uint2 v3 = *(const uint2*)(z16 + (size_t)s3 * 40 + hoff);
            const __half2* h;
            h = (const __half2*)&v0;
            { float2 f = __half22float2(h[0]); a[0]+=f.x; a[1]+=f.y; f = __half22float2(h[1]); a[2]+=f.x; a[3]+=f.y; }
            h = (const __half2*)&v1;
            { float2 f = __half22float2(h[0]); a[0]+=f.x; a[1]+=f.y; f = __half22float2(h[1]); a[2]+=f.x; a[3]+=f.y; }
            h = (const __half2*)&v2;
            { float2 f = __half22float2(h[0]); a[0]+=f.x; a[1]+=f.y; f = __half22float2(h[1]); a[2]+=f.x; a[3]+=f.y; }
            h = (const __half2*)&v3;
            { float2 f = __half22float2(h[0]); a[0]+=f.x; a[1]+=f.y; f = __half22float2(h[1]); a[2]+=f.x; a[3]+=f.y; }
        }
        for (; q < cnt; ++q) {
            int s0 = __shfl(myidx, gbase + q);
            uint2 v0 = *(const uint2*)(z16 + (size_t)s0 * 40 + hoff);
            const __half2* h = (const __half2*)&v0;
            float2 f = __half22float2(h[0]); a[0]+=f.x; a[1]+=f.y;
            f = __half22float2(h[1]); a[2]+=f.x; a[3]+=f.y;
        }
    }
    if (sub < 10) {
        uint2 sv = *(const uint2*)(z16 + (size_t)grp * 40 + hoff);
        const __half2* h = (const __half2*)&sv;
        float2 f0 = __half22float2(h[0]);
        float2 f1 = __half22float2(h[1]);
        float4 bb = *(const float4*)(bout + hoff);
        float4 o;
        o.x = f0.x + bb.x + a[0];
        o.y = f0.y + bb.y + a[1];
        o.z = f1.x + bb.z + a[2];
        o.w = f1.y + bb.w + a[3];
        *(float4*)(out + (size_t)grp * 40 + hoff) = o;
    }
}

// ---------------- MFMA GEMM: Y16[M][128] = fp16( A16[M][128] @ W[128][128] ) ----------------
// One wave per 16-row tile (strip-mined). W held in registers as 32 B-frags.
// Frag layouts (gfx950 16x16x32): A: row=lane&15, k=8*(lane>>4)+j
//                                 B: col=lane&15, k=8*(lane>>4)+j
//                                 D: col=lane&15, row=4*(lane>>4)+r
#define G128_WAVES 3128  // 782 blocks x 4 waves; 6250 tiles total
__global__ __launch_bounds__(256) void gemm128_mfma_kernel(
    const __half* __restrict__ A16, const float* __restrict__ W,
    __half* __restrict__ Y16) {
    const int wid = (blockIdx.x * 256 + threadIdx.x) >> 6;
    const int lane = threadIdx.x & 63;
    const int bl = lane & 15;
    const int bg = lane >> 4;

    // ---- load W into 32 B-frags (one-time per wave; W is L2-hot) ----
    f16x8 bf[8][4];
#pragma unroll
    for (int n = 0; n < 8; ++n) {
#pragma unroll
        for (int kk = 0; kk < 4; ++kk) {
            f16x8 t;
#pragma unroll
            for (int i = 0; i < 8; ++i) {
                float w = W[(size_t)(32 * kk + 8 * bg + i) * 128 + 16 * n + bl];
                t[i] = (_Float16)w;
            }
            bf[n][kk] = t;
        }
    }

    for (int tile = wid; tile < NN / 16; tile += G128_WAVES) {
        const int row0 = tile * 16;
        // A-frags: 4 x 16B loads; instr kk pulls one full 64B line per row
        const __half* Ap = A16 + (size_t)(row0 + bl) * 128 + 8 * bg;
        f16x8 af[4];
#pragma unroll
        for (int kk = 0; kk < 4; ++kk)
            af[kk] = *(const f16x8*)(Ap + 32 * kk);

        f32x4 acc[8];
#pragma unroll
        for (int n = 0; n < 8; ++n) acc[n] = (f32x4){0.f, 0.f, 0.f, 0.f};
#pragma unroll
        for (int kk = 0; kk < 4; ++kk) {
#pragma unroll
            for (int n = 0; n < 8; ++n)
                acc[n] = __builtin_amdgcn_mfma_f32_16x16x32_f16(af[kk], bf[n][kk], acc[n], 0, 0, 0);
        }
        // D store: lane l, frag n, reg r -> Y[row0 + 4*bg + r][16n + bl]
        __half* Yp = Y16 + (size_t)(row0 + 4 * bg) * 128 + bl;
#pragma unroll
        for (int n = 0; n < 8; ++n) {
#pragma unroll
            for (int r = 0; r < 4; ++r)
                Yp[(size_t)r * 128 + 16 * n] = __float2half(acc[n][r]);
        }
    }
}

// ---------------- GEMM: Z16[M][40] = fp16( A16[M][128] @ W[128][40] ) ----------------
__global__ __launch_bounds__(256) void gemm40_kernel(
    const __half* __restrict__ A16, const float* __restrict__ W,
    __half* __restrict__ Z16, int M) {
    __shared__ float As[64][132];
    __shared__ float Wls[128 * 40];
    const int t = threadIdx.x;
    const int br = blockIdx.x * 64;
#pragma unroll
    for (int i = 0; i < 5; ++i) {
        int idx = t + 256 * i;
        *(float4*)&Wls[idx * 4] = *(const float4*)(W + idx * 4);
    }
    {
        int r = t >> 2;
        int row = min(br + r, M - 1);
        const __half* Ap = A16 + (size_t)row * 128;
#pragma unroll
        for (int i = 0; i < 4; ++i) {
            int c = (t & 3) + 4 * i;
            uint4 v = *(const uint4*)(Ap + 8 * c);
            const __half2* h = (const __half2*)&v;
#pragma unroll
            for (int k = 0; k < 4; ++k) {
                float2 f = __half22float2(h[k]);
                As[r][8 * c + 2 * k] = f.x;
                As[r][8 * c + 2 * k + 1] = f.y;
            }
        }
    }
    __syncthreads();
    const int r = t >> 2;
    const int tn10 = (t & 3) * 10;
    float acc[10];
#pragma unroll
    for (int j = 0; j < 10; ++j) acc[j] = 0.f;
#pragma unroll 4
    for (int kk = 0; kk < 128; ++kk) {
        float a0 = As[r][kk];
        const float* wp = &Wls[kk * 40 + tn10];
#pragma unroll
        for (int j = 0; j < 10; ++j) acc[j] += a0 * wp[j];
    }
    int row = br + r;
    if (row < M) {
        __half* zp = Z16 + (size_t)row * 40 + tn10;
#pragma unroll
        for (int j = 0; j < 5; ++j) {
            __half2 hv = __float22half2_rn(make_float2(acc[2 * j], acc[2 * j + 1]));
            *(uint*)( (char*)zp + 4 * j ) = *(uint*)&hv;
        }
    }
}

extern "C" void kernel_launch(void* const* d_in, const int* in_sizes, int n_in,
                              void* d_out, int out_size, void* d_ws, size_t ws_size,
                              hipStream_t stream) {
    const float* h      = (const float*)d_in[0];
    const float* Ws     = (const float*)d_in[1];
    const float* bs     = (const float*)d_in[2];
    const float* W_out  = (const float*)d_in[3];
    const float* b_out  = (const float*)d_in[4];
    const int*   ei     = (const int*)d_in[5];
    float* out = (float*)d_out;

    char* p = (char*)d_ws;
    auto alloc = [&](size_t bytes) {
        char* r = p;
        p += (bytes + 255) & ~size_t(255);
        return r;
    };
    int* hist    = (int*)alloc((size_t)NPART * NN * 4);
    int* cursors = (int*)alloc((size_t)NPART * NN * 4);
    int* rowptr  = (int*)alloc((size_t)(NN + 1) * 4);
    int* bsums   = (int*)alloc(128 * 4);
    int* esrc    = (int*)alloc((size_t)NE * 4);
    __half* X16  = (__half*)alloc((size_t)NN * 128 * 2);
    __half* Y16  = (__half*)alloc((size_t)NN * 128 * 2 + 256);

    // ---- CSR build ----
    hipMemsetAsync(hist, 0, (size_t)NPART * NN * 4, stream);
    const int eblocks = (NE / 4 + 255) / 256;
    hist_kernel<<<eblocks, 256, 0, stream>>>(ei, hist);
    int nb = (NN + 1023) / 1024;
    scan_partial<<<nb, 256, 0, stream>>>(hist, esrc /*scratch*/, bsums);
    scan_sums<<<1, 128, 0, stream>>>(bsums, nb);
    scan_finalize<<<(NN + 256) / 256, 256, 0, stream>>>(esrc, bsums, hist, rowptr, cursors);
    fill_kernel<<<eblocks, 256, 0, stream>>>(ei, cursors, esrc);

    // ---- h -> fp16 ----
    cvt16_kernel<<<(NN * 128 / 8 + 255) / 256, 256, 0, stream>>>(h, X16);

    // ---- layers 0..3: y = x@W (MFMA, fp16); x' = y + agg(y) + b ----
    const int spmm_grid = (NN * 16 + 255) / 256;
    for (int l = 0; l < 4; ++l) {
        gemm128_mfma_kernel<<<G128_WAVES / 4, 256, 0, stream>>>(
            X16, Ws + (size_t)l * 128 * 128, Y16);
        spmm128_kernel<<<spmm_grid, 256, 0, stream>>>(
            Y16, rowptr, esrc, bs + (size_t)l * 128, X16);
    }
    // ---- layer 4: z = x4@W_out; out = z + agg(z) + b_out ----
    gemm40_kernel<<<(NN + 63) / 64, 256, 0, stream>>>(X16, W_out, Y16 /*as Z16*/, NN);
    spmm40_kernel<<<spmm_grid, 256, 0, stream>>>(Y16, rowptr, esrc, b_out, out);
}